// Round 9
// baseline (271.722 us; speedup 1.0000x reference)
//
#include <hip/hip_runtime.h>
#include <hip/hip_cooperative_groups.h>
#include <math.h>

namespace cg = cooperative_groups;

#define BB   64
#define SS   576
#define DD   768
#define KTOP 63
#define KEEP 64
#define HH   128
#define NROW (BB*KEEP + BB)   // 4160 = 65*64
#define SCH  24               // 576 = 24*24

typedef unsigned long long ull;
typedef _Float16 h2 __attribute__((ext_vector_type(2)));

static __device__ __forceinline__ float DOT2(h2 a, h2 b, float c) {
#if __has_builtin(__builtin_amdgcn_fdot2)
  return __builtin_amdgcn_fdot2(a, b, c, false);
#else
  return fmaf((float)a[1], (float)b[1], fmaf((float)a[0], (float)b[0], c));
#endif
}
static __device__ __forceinline__ unsigned PK(float x, float y) {
  return __builtin_bit_cast(unsigned, __builtin_amdgcn_cvt_pkrtz(x, y));
}
static __device__ __forceinline__ h2 BC(unsigned u) {
  return __builtin_bit_cast(h2, u);
}

// One cooperative kernel, 256 blocks x 256 threads, 7 phases, 6 grid syncs.
// R9 fix: P1 now covers ALL 36864 score rows (36 per wave, was 9 — R8 bug).
__global__ __launch_bounds__(256, 1) void k_mega(
    const float* __restrict__ cls, const float* __restrict__ fm,
    const float* __restrict__ W1, const float* __restrict__ b1,
    const float* __restrict__ W2, const float* __restrict__ b2,
    float* __restrict__ out,
    float* __restrict__ scores, int* __restrict__ idx,
    float* __restrict__ wprime, float* __restrict__ epart,
    float* __restrict__ extra, float* __restrict__ partial,
    unsigned* __restrict__ H16)
{
  cg::grid_group grid = cg::this_grid();
  __shared__ union {
    ull keys[SS];                                            //  4.6 KB (P2)
    struct { _Float16 Xs[64][68]; unsigned Wp[32][132]; } a1; // 25.6 KB (P5)
    struct { _Float16 Hs[64][132]; unsigned Wp[64][132]; } a2;// 50.7 KB (P7)
  } sh;
  __shared__ const float* rowptr[64];
  __shared__ float redA[4], redB[4];

  const int tid = threadIdx.x;
  const int B = blockIdx.x;
  const int lane = tid & 63, wid = tid >> 6;

  // ================= P1: cls-attn scores (f64 acc, 2-row ILP) =================
  // 1024 waves x 36 rows = 36864 = BB*SS rows.
  {
    int wv = (B << 2) + wid;                 // wave id 0..1023
#pragma unroll 2
    for (int k = 0; k < 36; k += 2) {
      int rowA = wv + (k << 10), rowB = rowA + 1024;
      int bA = rowA / SS, sA = rowA - bA * SS;
      int bB = rowB / SS, sB = rowB - bB * SS;
      const float4* fA = (const float4*)(fm + ((size_t)bA * SS + sA) * DD);
      const float4* cA = (const float4*)(cls + (size_t)bA * DD);
      const float4* fB = (const float4*)(fm + ((size_t)bB * SS + sB) * DD);
      const float4* cB = (const float4*)(cls + (size_t)bB * DD);
      double aA = 0.0, aB = 0.0;
#pragma unroll
      for (int j = 0; j < 3; ++j) {
        float4 f1 = fA[lane + 64 * j], c1 = cA[lane + 64 * j];
        float4 f2 = fB[lane + 64 * j], c2 = cB[lane + 64 * j];
        aA += (double)f1.x*c1.x + (double)f1.y*c1.y + (double)f1.z*c1.z + (double)f1.w*c1.w;
        aB += (double)f2.x*c2.x + (double)f2.y*c2.y + (double)f2.z*c2.z + (double)f2.w*c2.w;
      }
#pragma unroll
      for (int off = 32; off > 0; off >>= 1) {
        aA += __shfl_down(aA, off, 64);
        aB += __shfl_down(aB, off, 64);
      }
      if (lane == 0) { scores[rowA] = (float)aA; scores[rowB] = (float)aB; }
    }
  }
  grid.sync();

  // ================= P2: rank top-63 + masked-softmax weights =================
  if (B < BB) {
    int b = B;
    for (int s = tid; s < SS; s += 256) {
      unsigned u = __float_as_uint(scores[(size_t)b * SS + s]);
      u = (u & 0x80000000u) ? ~u : (u | 0x80000000u);   // order-preserving map
      sh.keys[s] = ((ull)u << 32) | (ull)(0xFFFFFFFFu - (unsigned)s);
    }
    __syncthreads();
    int s0 = tid, s1 = tid + 256, s2 = tid + 512;
    bool h3 = (s2 < SS);
    ull k0 = sh.keys[s0], k1 = sh.keys[s1], k2 = h3 ? sh.keys[s2] : 0ull;
    int r0 = 0, r1 = 0, r2 = 0;
#pragma unroll 8
    for (int i = 0; i < SS; ++i) {
      ull kk = sh.keys[i];
      r0 += kk > k0; r1 += kk > k1; r2 += kk > k2;
    }
    float sc0 = scores[(size_t)b * SS + s0];
    float sc1 = scores[(size_t)b * SS + s1];
    float sc2 = h3 ? scores[(size_t)b * SS + s2] : -1e30f;
    bool sel0 = r0 < KTOP, sel1 = r1 < KTOP, sel2 = h3 && (r2 < KTOP);
    if (sel0) idx[b * KEEP + r0] = s0;
    if (sel1) idx[b * KEEP + r1] = s1;
    if (sel2) idx[b * KEEP + r2] = s2;
    // max over unselected (selected logits are sc-10000 -> never the max)
    float m = sel0 ? -1e30f : sc0;
    if (!sel1) m = fmaxf(m, sc1);
    if (h3 && !sel2) m = fmaxf(m, sc2);
#pragma unroll
    for (int off = 32; off; off >>= 1) m = fmaxf(m, __shfl_xor(m, off, 64));
    if (lane == 0) redA[wid] = m;
    __syncthreads();
    float M = fmaxf(fmaxf(redA[0], redA[1]), fmaxf(redA[2], redA[3]));
    float e0 = sel0 ? 0.f : expf(sc0 - M);
    float e1 = sel1 ? 0.f : expf(sc1 - M);
    float e2 = (h3 && !sel2) ? expf(sc2 - M) : 0.f;
    float z = e0 + e1 + e2;
#pragma unroll
    for (int off = 32; off; off >>= 1) z += __shfl_xor(z, off, 64);
    if (lane == 0) redB[wid] = z;
    __syncthreads();
    float Z = (redB[0] + redB[1]) + (redB[2] + redB[3]);
    wprime[(size_t)b * SS + s0] = e0 / Z;
    wprime[(size_t)b * SS + s1] = e1 / Z;
    if (h3) wprime[(size_t)b * SS + s2] = e2 / Z;
  }
  grid.sync();

  // ================= P3: pooled-token partial sums (24-row chunks) ============
  for (int t = B; t < BB * SCH; t += 256) {            // 6 tasks per block
    int b = t / SCH, p = t - b * SCH;
    if (tid < 192) {
      const float* fbase = fm + ((size_t)b * SS + p * SCH) * DD + tid * 4;
      const float* wp = wprime + (size_t)b * SS + p * SCH;
      float4 acc = make_float4(0.f, 0.f, 0.f, 0.f);
#pragma unroll
      for (int r = 0; r < SCH; ++r) {                  // 24 loads in flight
        float w = wp[r];
        float4 v = *(const float4*)(fbase + (size_t)r * DD);
        acc.x = fmaf(w, v.x, acc.x); acc.y = fmaf(w, v.y, acc.y);
        acc.z = fmaf(w, v.z, acc.z); acc.w = fmaf(w, v.w, acc.w);
      }
      *(float4*)(epart + (size_t)(b * SCH + p) * DD + tid * 4) = acc;
    }
  }
  grid.sync();

  // ================= P4: reduce 24 partials -> extra token ====================
  {
    int i = B * 256 + tid;
    if (i < BB * DD / 4) {
      int b = i / (DD / 4), c4 = i - b * (DD / 4);
      const float4* P = (const float4*)epart;
      float4 s = make_float4(0.f, 0.f, 0.f, 0.f);
#pragma unroll
      for (int p = 0; p < SCH; ++p) {
        float4 t4 = P[(size_t)(b * SCH + p) * (DD / 4) + c4];
        s.x += t4.x; s.y += t4.y; s.z += t4.z; s.w += t4.w;
      }
      ((float4*)extra)[i] = s;
    }
  }
  grid.sync();

  // ================= P5: ae1 partials (f16 dot2, 64r x 128c x 64k tasks) ======
  for (int t = B; t < 65 * 12; t += 256) {             // <=4 tasks per block
    int g = t % 65, y = t / 65;
    __syncthreads();                                   // prev task LDS consumed
    if (tid < 64) {
      const float* p;
      if (g < BB) p = (tid < KTOP) ? fm + ((size_t)g * SS + idx[g * KEEP + tid]) * DD
                                   : extra + (size_t)g * DD;
      else        p = cls + (size_t)tid * DD;
      rowptr[tid] = p;
    }
    __syncthreads();
    int kb = y * 64;
#pragma unroll
    for (int i = 0; i < 4; ++i) {                      // X: 64 rows x 64 k -> f16
      int id = tid + 256 * i;
      int k4 = id & 15, r = id >> 4;
      float4 v = *(const float4*)(rowptr[r] + kb + k4 * 4);
      uint2 o = { PK(v.x, v.y), PK(v.z, v.w) };
      *(uint2*)&sh.a1.Xs[r][k4 * 4] = o;
    }
#pragma unroll
    for (int i = 0; i < 4; ++i) {                      // W1: 32 kp x 128 c pairs
      int id = tid + 256 * i;
      int c4 = id & 31, kp = id >> 5;
      const float* w0 = W1 + (size_t)(kb + 2 * kp) * HH + c4 * 4;
      float4 a = *(const float4*)w0;
      float4 bq = *(const float4*)(w0 + HH);
      uint4 o = { PK(a.x, bq.x), PK(a.y, bq.y), PK(a.z, bq.z), PK(a.w, bq.w) };
      *(uint4*)&sh.a1.Wp[kp][c4 * 4] = o;
    }
    __syncthreads();
    int ty = tid >> 4, tx = tid & 15;
    int rr0 = ty * 4;
    float acc[4][8] = {};
#pragma unroll 4
    for (int q = 0; q < 16; ++q) {                     // 4 k per iter
      uint2 xr[4];
#pragma unroll
      for (int i = 0; i < 4; ++i) xr[i] = *(const uint2*)&sh.a1.Xs[rr0 + i][q * 4];
      uint4 wa0 = *(const uint4*)&sh.a1.Wp[2 * q][tx * 4];
      uint4 wa1 = *(const uint4*)&sh.a1.Wp[2 * q][64 + tx * 4];
      uint4 wb0 = *(const uint4*)&sh.a1.Wp[2 * q + 1][tx * 4];
      uint4 wb1 = *(const uint4*)&sh.a1.Wp[2 * q + 1][64 + tx * 4];
#pragma unroll
      for (int i = 0; i < 4; ++i) {
        h2 a0 = BC(xr[i].x), a1v = BC(xr[i].y);
        acc[i][0] = DOT2(a1v, BC(wb0.x), DOT2(a0, BC(wa0.x), acc[i][0]));
        acc[i][1] = DOT2(a1v, BC(wb0.y), DOT2(a0, BC(wa0.y), acc[i][1]));
        acc[i][2] = DOT2(a1v, BC(wb0.z), DOT2(a0, BC(wa0.z), acc[i][2]));
        acc[i][3] = DOT2(a1v, BC(wb0.w), DOT2(a0, BC(wa0.w), acc[i][3]));
        acc[i][4] = DOT2(a1v, BC(wb1.x), DOT2(a0, BC(wa1.x), acc[i][4]));
        acc[i][5] = DOT2(a1v, BC(wb1.y), DOT2(a0, BC(wa1.y), acc[i][5]));
        acc[i][6] = DOT2(a1v, BC(wb1.z), DOT2(a0, BC(wa1.z), acc[i][6]));
        acc[i][7] = DOT2(a1v, BC(wb1.w), DOT2(a0, BC(wa1.w), acc[i][7]));
      }
    }
    float* P = partial + (size_t)y * ((size_t)NROW * HH);
#pragma unroll
    for (int i = 0; i < 4; ++i) {
      size_t row = (size_t)(g * 64 + rr0 + i);
      float4 v0 = make_float4(acc[i][0], acc[i][1], acc[i][2], acc[i][3]);
      float4 v1 = make_float4(acc[i][4], acc[i][5], acc[i][6], acc[i][7]);
      *(float4*)&P[row * HH + tx * 4] = v0;
      *(float4*)&P[row * HH + 64 + tx * 4] = v1;
    }
  }
  grid.sync();

  // ================= P6: H(f16) = tanh(sum of 12 partials + b1) ===============
  for (int i4 = B * 256 + tid; i4 < NROW * HH / 4; i4 += 65536) {
    const float4* P = (const float4*)partial;
    float4 s = P[i4];
#pragma unroll
    for (int p = 1; p < 12; ++p) {
      float4 t4 = P[(size_t)p * (NROW * HH / 4) + i4];
      s.x += t4.x; s.y += t4.y; s.z += t4.z; s.w += t4.w;
    }
    float4 bv = ((const float4*)b1)[i4 & 31];          // HH/4 = 32 f4 per row
    s.x = tanhf(s.x + bv.x); s.y = tanhf(s.y + bv.y);
    s.z = tanhf(s.z + bv.z); s.w = tanhf(s.w + bv.w);
    uint2 o = { PK(s.x, s.y), PK(s.z, s.w) };
    ((uint2*)H16)[i4] = o;
  }
  grid.sync();

  // ================= P7: out = H @ W2 + b2 (f16 dot2, 64r x 128c tasks) =======
  for (int t = B; t < 65 * 6; t += 256) {              // <=2 tasks per block
    int g = t % 65, cb = t / 65;
    __syncthreads();
#pragma unroll
    for (int i = 0; i < 8; ++i) {                      // H tile: 64 x 128 f16
      int id = tid + 256 * i;
      int k4 = id & 31, r = id >> 5;
      uint2 v = ((const uint2*)H16)[(size_t)(g * 64 + r) * (HH / 4) + k4];
      *(uint2*)&sh.a2.Hs[r][k4 * 4] = v;
    }
#pragma unroll
    for (int i = 0; i < 8; ++i) {                      // W2: 64 kp x 128 c pairs
      int id = tid + 256 * i;
      int c4 = id & 31, kp = id >> 5;
      const float* w0 = W2 + (size_t)(2 * kp) * DD + cb * 128 + c4 * 4;
      float4 a = *(const float4*)w0;
      float4 bq = *(const float4*)(w0 + DD);
      uint4 o = { PK(a.x, bq.x), PK(a.y, bq.y), PK(a.z, bq.z), PK(a.w, bq.w) };
      *(uint4*)&sh.a2.Wp[kp][c4 * 4] = o;
    }
    __syncthreads();
    int ty = tid >> 4, tx = tid & 15;
    int rr0 = ty * 4;
    float acc[4][8] = {};
#pragma unroll 4
    for (int q = 0; q < 32; ++q) {                     // K = 128
      uint2 xr[4];
#pragma unroll
      for (int i = 0; i < 4; ++i) xr[i] = *(const uint2*)&sh.a2.Hs[rr0 + i][q * 4];
      uint4 wa0 = *(const uint4*)&sh.a2.Wp[2 * q][tx * 4];
      uint4 wa1 = *(const uint4*)&sh.a2.Wp[2 * q][64 + tx * 4];
      uint4 wb0 = *(const uint4*)&sh.a2.Wp[2 * q + 1][tx * 4];
      uint4 wb1 = *(const uint4*)&sh.a2.Wp[2 * q + 1][64 + tx * 4];
#pragma unroll
      for (int i = 0; i < 4; ++i) {
        h2 a0 = BC(xr[i].x), a1v = BC(xr[i].y);
        acc[i][0] = DOT2(a1v, BC(wb0.x), DOT2(a0, BC(wa0.x), acc[i][0]));
        acc[i][1] = DOT2(a1v, BC(wb0.y), DOT2(a0, BC(wa0.y), acc[i][1]));
        acc[i][2] = DOT2(a1v, BC(wb0.z), DOT2(a0, BC(wa0.z), acc[i][2]));
        acc[i][3] = DOT2(a1v, BC(wb0.w), DOT2(a0, BC(wa0.w), acc[i][3]));
        acc[i][4] = DOT2(a1v, BC(wb1.x), DOT2(a0, BC(wa1.x), acc[i][4]));
        acc[i][5] = DOT2(a1v, BC(wb1.y), DOT2(a0, BC(wa1.y), acc[i][5]));
        acc[i][6] = DOT2(a1v, BC(wb1.z), DOT2(a0, BC(wa1.z), acc[i][6]));
        acc[i][7] = DOT2(a1v, BC(wb1.w), DOT2(a0, BC(wa1.w), acc[i][7]));
      }
    }
    float4 bv0 = *(const float4*)&b2[cb * 128 + tx * 4];
    float4 bv1 = *(const float4*)&b2[cb * 128 + 64 + tx * 4];
#pragma unroll
    for (int i = 0; i < 4; ++i) {
      size_t row = (size_t)(g * 64 + rr0 + i);
      float4 y0 = make_float4(acc[i][0] + bv0.x, acc[i][1] + bv0.y,
                              acc[i][2] + bv0.z, acc[i][3] + bv0.w);
      float4 y1 = make_float4(acc[i][4] + bv1.x, acc[i][5] + bv1.y,
                              acc[i][6] + bv1.z, acc[i][7] + bv1.w);
      *(float4*)&out[row * DD + cb * 128 + tx * 4] = y0;
      *(float4*)&out[row * DD + cb * 128 + 64 + tx * 4] = y1;
    }
  }
}

extern "C" void kernel_launch(void* const* d_in, const int* in_sizes, int n_in,
                              void* d_out, int out_size, void* d_ws, size_t ws_size,
                              hipStream_t stream)
{
  const float* cls = (const float*)d_in[0];
  const float* fm  = (const float*)d_in[1];
  const float* W1  = (const float*)d_in[2];
  const float* b1  = (const float*)d_in[3];
  const float* W2  = (const float*)d_in[4];
  const float* b2  = (const float*)d_in[5];
  float* out = (float*)d_out;

  char* ws = (char*)d_ws;
  float*    scores  = (float*)ws;                       //   147456 B
  int*      idx     = (int*)(ws + 147456);              //    16384 B
  float*    extra   = (float*)(ws + 163840);            //   196608 B
  float*    wprime  = (float*)(ws + 360448);            //   147456 B
  float*    epart   = (float*)(ws + 507904);            //  4718592 B
  float*    partial = (float*)(ws + 5226496);           // 12 x 2129920 B
  unsigned* H16     = (unsigned*)(ws + 5226496 + 12 * 2129920);  // 1064960 B

  void* args[] = { (void*)&cls, (void*)&fm, (void*)&W1, (void*)&b1,
                   (void*)&W2, (void*)&b2, (void*)&out,
                   (void*)&scores, (void*)&idx, (void*)&wprime, (void*)&epart,
                   (void*)&extra, (void*)&partial, (void*)&H16 };
  hipLaunchCooperativeKernel((const void*)k_mega, dim3(256), dim3(256), args, 0, stream);
}

// Round 10
// 89.973 us; speedup vs baseline: 3.0200x; 3.0200x over previous
//
#include <hip/hip_runtime.h>
#include <math.h>

#define BB   64
#define SS   576
#define DD   768
#define KTOP 63
#define KEEP 64
#define HH   128
#define NROW (BB*KEEP + BB)   // 4160 = 65*64
#define SCH  24               // pooled-sum chunk count (grid.y)

typedef unsigned long long ull;

// ---------------- K1: cls attention scores (f64 accumulate for exact ranking) ---
__global__ __launch_bounds__(256) void k_scores(const float* __restrict__ cls,
                                                const float* __restrict__ fm,
                                                float* __restrict__ scores)
{
  int gw = (blockIdx.x * blockDim.x + threadIdx.x) >> 6;   // one wave per (b,s)
  int lane = threadIdx.x & 63;
  if (gw >= BB * SS) return;
  int b = gw / SS, s = gw - b * SS;
  const float4* frow = (const float4*)(fm + ((size_t)b * SS + s) * DD);
  const float4* crow = (const float4*)(cls + (size_t)b * DD);
  double acc = 0.0;
#pragma unroll
  for (int j = 0; j < 3; ++j) {
    float4 f = frow[lane + 64 * j];
    float4 c = crow[lane + 64 * j];
    acc += (double)f.x * c.x + (double)f.y * c.y + (double)f.z * c.z + (double)f.w * c.w;
  }
#pragma unroll
  for (int off = 32; off > 0; off >>= 1) acc += __shfl_down(acc, off, 64);
  if (lane == 0) scores[(size_t)b * SS + s] = (float)acc;
}

// ---------------- K2: rank top-63 + softmax weights + survivor compaction ------
// One 576-thread block per batch. rank = #{keys > key_s} (unique keys -> exact
// jax.lax.top_k order). w' = e/Z (0 for selected, matching f32 exp(-1e4)
// underflow). Rows with w' > 1e-10 are compacted (stable, ascending s) into
// (cidx, cw) for the sparse pooled-sum pass.
__global__ __launch_bounds__(576) void k_rank(const float* __restrict__ scores,
                                              int* __restrict__ idxout,
                                              int* __restrict__ cidx,
                                              float* __restrict__ cw,
                                              int* __restrict__ ccount)
{
  __shared__ ull keys[SS];
  __shared__ float redm[9], redz[9];
  __shared__ unsigned wcnt[9];
  int b = blockIdx.x, tid = threadIdx.x;          // tid == s (0..575)
  int lane = tid & 63, wid = tid >> 6;            // 9 waves
  float sc = scores[(size_t)b * SS + tid];
  unsigned int u = __float_as_uint(sc);
  u = (u & 0x80000000u) ? ~u : (u | 0x80000000u); // order-preserving map
  ull key = ((ull)u << 32) | (ull)(0xFFFFFFFFu - (unsigned)tid);
  keys[tid] = key;
  __syncthreads();
  int rank = 0;
#pragma unroll 8
  for (int s = 0; s < SS; ++s) rank += (keys[s] > key) ? 1 : 0;   // LDS broadcast
  bool sel = rank < KTOP;
  if (sel) idxout[b * KEEP + rank] = tid;
  // max over unselected (selected logits are sc-10000 -> never the max)
  float m = sel ? -1e30f : sc;
#pragma unroll
  for (int off = 32; off; off >>= 1) m = fmaxf(m, __shfl_xor(m, off, 64));
  if (lane == 0) redm[wid] = m;
  __syncthreads();
  float M = redm[0];
#pragma unroll
  for (int i = 1; i < 9; ++i) M = fmaxf(M, redm[i]);
  float e = sel ? 0.f : expf(sc - M);
  float z = e;
#pragma unroll
  for (int off = 32; off; off >>= 1) z += __shfl_xor(z, off, 64);
  if (lane == 0) redz[wid] = z;
  __syncthreads();
  float Z = redz[0];
#pragma unroll
  for (int i = 1; i < 9; ++i) Z += redz[i];
  float w = e / Z;
  // ---- compaction of survivors (w > 1e-10); skipped mass <= ~5e-9 ----
  bool keep = w > 1e-10f;
  ull ball = __ballot(keep);
  int wpre = __popcll(ball & ((1ull << lane) - 1ull));
  if (lane == 0) wcnt[wid] = (unsigned)__popcll(ball);
  __syncthreads();
  int base = 0;
#pragma unroll
  for (int i = 0; i < 9; ++i) base += (i < wid) ? (int)wcnt[i] : 0;
  if (keep) {
    int pos = base + wpre;
    cidx[(size_t)b * SS + pos] = tid;
    cw[(size_t)b * SS + pos] = w;
  }
  if (tid == 0) {
    int tot = 0;
#pragma unroll
    for (int i = 0; i < 9; ++i) tot += (int)wcnt[i];
    ccount[b] = tot;
  }
}

// ---------------- K3: sparse pooled-token partial sums -------------------------
// grid (64, 24) x 192 thr. Chunk p sums survivor rows r = p, p+24, ... Each row
// read is a coalesced 3 KB segment (192 x float4).
__global__ __launch_bounds__(192) void k_extra2(const int* __restrict__ cidx,
                                                const float* __restrict__ cw,
                                                const int* __restrict__ ccount,
                                                const float* __restrict__ fm,
                                                float* __restrict__ epart)
{
  int b = blockIdx.x, p = blockIdx.y, tid = threadIdx.x;   // tid = float4 col
  int n = ccount[b];
  const float* fb = fm + (size_t)b * SS * DD + tid * 4;
  float4 acc = make_float4(0.f, 0.f, 0.f, 0.f);
  for (int r = p; r < n; r += SCH) {
    float w = cw[(size_t)b * SS + r];                      // uniform broadcast
    int s = cidx[(size_t)b * SS + r];
    float4 v = *(const float4*)(fb + (size_t)s * DD);
    acc.x = fmaf(w, v.x, acc.x); acc.y = fmaf(w, v.y, acc.y);
    acc.z = fmaf(w, v.z, acc.z); acc.w = fmaf(w, v.w, acc.w);
  }
  *(float4*)(epart + (size_t)(b * SCH + p) * DD + tid * 4) = acc;
}

// ---------------- K4: partial[y] = X(rows) @ W1[K-chunk y] ---------------------
// Block = 64 rows x 128 cols, K-chunk 64. LDS 51.7 KB -> 3 blocks/CU.
// Row 63 of batch tiles (pooled token) is built in-staging as the sum of the 24
// epart chunk rows (k_ered fused away).
template<int CPB>
__global__ __launch_bounds__(256, 3) void k_ae1(const float* __restrict__ fm,
                                                const float* __restrict__ cls,
                                                const float* __restrict__ epart,
                                                const int* __restrict__ idxin,
                                                const float* __restrict__ W1,
                                                float* __restrict__ partial)
{
  __shared__ float Xs[64][68];         // 17.0 KB
  __shared__ float Ws[64][132];        // 33.8 KB
  __shared__ const float* rowptr[64];
  int g = blockIdx.x;                  // row group: rows g*64 .. +63
  int tid = threadIdx.x;
  bool batch = (g < BB);

  if (tid < 64) {
    const float* p;
    if (batch) {
      p = (tid < KTOP) ? fm + ((size_t)g * SS + idxin[g * KEEP + tid]) * DD
                       : epart + (size_t)(g * SCH) * DD;   // placeholder (row 63 rebuilt)
    } else {
      p = cls + (size_t)tid * DD;
    }
    rowptr[tid] = p;
  }

  int ty = tid >> 5, tx = tid & 31;
  int r0 = ty * 8, c0 = tx * 4;
  float acc[8][4] = {};

  for (int cc = 0; cc < CPB; ++cc) {
    int kb = (blockIdx.y * CPB + cc) * 64;
    __syncthreads();                   // rowptr ready / previous tile consumed
#pragma unroll
    for (int i = 0; i < 4; ++i) {      // X tile: 64 rows x 16 float4
      int f4 = tid + 256 * i;
      int r = f4 >> 4, k4 = f4 & 15;
      if (!batch || r != 63)
        *(float4*)&Xs[r][k4 * 4] = *(const float4*)(rowptr[r] + kb + k4 * 4);
    }
    if (batch && tid < 16) {           // pooled-token row: sum 24 epart chunks
      float4 s = make_float4(0.f, 0.f, 0.f, 0.f);
#pragma unroll
      for (int p = 0; p < SCH; ++p) {
        float4 t = *(const float4*)(epart + (size_t)(g * SCH + p) * DD + kb + tid * 4);
        s.x += t.x; s.y += t.y; s.z += t.z; s.w += t.w;
      }
      *(float4*)&Xs[63][tid * 4] = s;
    }
#pragma unroll
    for (int i = 0; i < 8; ++i) {      // W1 chunk: 64 rows x 32 float4
      int f4 = tid + 256 * i;
      int wr = f4 >> 5, c4 = f4 & 31;
      *(float4*)&Ws[wr][c4 * 4] =
          *(const float4*)(W1 + (size_t)(kb + wr) * HH + c4 * 4);
    }
    __syncthreads();
#pragma unroll
    for (int q = 0; q < 16; ++q) {     // 64 K per chunk
      float4 xv[8], wv[4];
#pragma unroll
      for (int i = 0; i < 8; ++i) xv[i] = *(const float4*)&Xs[r0 + i][q * 4];
#pragma unroll
      for (int j = 0; j < 4; ++j) wv[j] = *(const float4*)&Ws[q * 4 + j][c0];
#pragma unroll
      for (int i = 0; i < 8; ++i) {
        float x;
        x = xv[i].x;
        acc[i][0] = fmaf(x, wv[0].x, acc[i][0]); acc[i][1] = fmaf(x, wv[0].y, acc[i][1]);
        acc[i][2] = fmaf(x, wv[0].z, acc[i][2]); acc[i][3] = fmaf(x, wv[0].w, acc[i][3]);
        x = xv[i].y;
        acc[i][0] = fmaf(x, wv[1].x, acc[i][0]); acc[i][1] = fmaf(x, wv[1].y, acc[i][1]);
        acc[i][2] = fmaf(x, wv[1].z, acc[i][2]); acc[i][3] = fmaf(x, wv[1].w, acc[i][3]);
        x = xv[i].z;
        acc[i][0] = fmaf(x, wv[2].x, acc[i][0]); acc[i][1] = fmaf(x, wv[2].y, acc[i][1]);
        acc[i][2] = fmaf(x, wv[2].z, acc[i][2]); acc[i][3] = fmaf(x, wv[2].w, acc[i][3]);
        x = xv[i].w;
        acc[i][0] = fmaf(x, wv[3].x, acc[i][0]); acc[i][1] = fmaf(x, wv[3].y, acc[i][1]);
        acc[i][2] = fmaf(x, wv[3].z, acc[i][2]); acc[i][3] = fmaf(x, wv[3].w, acc[i][3]);
      }
    }
  }
  float* P = partial + (size_t)(CPB == 1 ? blockIdx.y : 0) * ((size_t)NROW * HH);
#pragma unroll
  for (int i = 0; i < 8; ++i) {
    float4 v = make_float4(acc[i][0], acc[i][1], acc[i][2], acc[i][3]);
    *(float4*)&P[(size_t)(g * 64 + r0 + i) * HH + c0] = v;
  }
}

// ---------------- K5: H = tanh(sum(partials) + b1) -----------------------------
template<int NP>
__global__ __launch_bounds__(256) void k_hred(const float* __restrict__ partial,
                                              const float* __restrict__ b1,
                                              float* __restrict__ H)
{
  int i4 = blockIdx.x * 256 + threadIdx.x;          // float4 index, 133120 total
  const float4* P = (const float4*)partial;
  float4 s = P[i4];
#pragma unroll
  for (int p = 1; p < NP; ++p) {
    float4 t = P[(size_t)p * (NROW * HH / 4) + i4];
    s.x += t.x; s.y += t.y; s.z += t.z; s.w += t.w;
  }
  float4 bv = ((const float4*)b1)[i4 & 31];         // HH/4 = 32 float4 per row
  s.x = tanhf(s.x + bv.x); s.y = tanhf(s.y + bv.y);
  s.z = tanhf(s.z + bv.z); s.w = tanhf(s.w + bv.w);
  ((float4*)H)[i4] = s;
}

// ---------------- K6: out = H @ W2 + b2 ----------------------------------------
// Block = 64 rows x 64 cols, K=128. LDS 68.6 KB -> 2 blocks/CU. grid (65, 12).
__global__ __launch_bounds__(256, 2) void k_ae2(const float* __restrict__ H,
                                                const float* __restrict__ W2,
                                                const float* __restrict__ b2,
                                                float* __restrict__ out)
{
  __shared__ float Hs[64][132];        // 33.8 KB
  __shared__ float Ws[128][68];        // 34.8 KB
  int g = blockIdx.x;
  int cb = blockIdx.y;                 // column chunk: cols cb*64 .. +63
  int tid = threadIdx.x;

#pragma unroll
  for (int i = 0; i < 8; ++i) {        // H tile: 64 rows x 32 float4
    int f4 = tid + 256 * i;
    int r = f4 >> 5, c4 = f4 & 31;
    *(float4*)&Hs[r][c4 * 4] = *(const float4*)(H + (size_t)(g * 64 + r) * HH + c4 * 4);
  }
#pragma unroll
  for (int i = 0; i < 8; ++i) {        // W2 slice: 128 rows x 16 float4
    int f4 = tid + 256 * i;
    int wr = f4 >> 4, c4 = f4 & 15;
    *(float4*)&Ws[wr][c4 * 4] =
        *(const float4*)(W2 + (size_t)wr * DD + cb * 64 + c4 * 4);
  }
  __syncthreads();

  int ty = tid >> 4, tx = tid & 15;
  int r0 = ty * 4, c0 = tx * 4;
  float acc[4][4] = {};
#pragma unroll 4
  for (int q = 0; q < 32; ++q) {       // K = 128
    float4 xv[4], wv[4];
#pragma unroll
    for (int i = 0; i < 4; ++i) xv[i] = *(const float4*)&Hs[r0 + i][q * 4];
#pragma unroll
    for (int j = 0; j < 4; ++j) wv[j] = *(const float4*)&Ws[q * 4 + j][c0];
#pragma unroll
    for (int i = 0; i < 4; ++i) {
      float x;
      x = xv[i].x;
      acc[i][0] = fmaf(x, wv[0].x, acc[i][0]); acc[i][1] = fmaf(x, wv[0].y, acc[i][1]);
      acc[i][2] = fmaf(x, wv[0].z, acc[i][2]); acc[i][3] = fmaf(x, wv[0].w, acc[i][3]);
      x = xv[i].y;
      acc[i][0] = fmaf(x, wv[1].x, acc[i][0]); acc[i][1] = fmaf(x, wv[1].y, acc[i][1]);
      acc[i][2] = fmaf(x, wv[1].z, acc[i][2]); acc[i][3] = fmaf(x, wv[1].w, acc[i][3]);
      x = xv[i].z;
      acc[i][0] = fmaf(x, wv[2].x, acc[i][0]); acc[i][1] = fmaf(x, wv[2].y, acc[i][1]);
      acc[i][2] = fmaf(x, wv[2].z, acc[i][2]); acc[i][3] = fmaf(x, wv[2].w, acc[i][3]);
      x = xv[i].w;
      acc[i][0] = fmaf(x, wv[3].x, acc[i][0]); acc[i][1] = fmaf(x, wv[3].y, acc[i][1]);
      acc[i][2] = fmaf(x, wv[3].z, acc[i][2]); acc[i][3] = fmaf(x, wv[3].w, acc[i][3]);
    }
  }
  float4 bv = *(const float4*)&b2[cb * 64 + c0];
#pragma unroll
  for (int i = 0; i < 4; ++i) {
    float4 y = make_float4(acc[i][0] + bv.x, acc[i][1] + bv.y,
                           acc[i][2] + bv.z, acc[i][3] + bv.w);
    *(float4*)&out[(size_t)(g * 64 + r0 + i) * DD + cb * 64 + c0] = y;
  }
}

extern "C" void kernel_launch(void* const* d_in, const int* in_sizes, int n_in,
                              void* d_out, int out_size, void* d_ws, size_t ws_size,
                              hipStream_t stream)
{
  const float* cls = (const float*)d_in[0];
  const float* fm  = (const float*)d_in[1];
  const float* W1  = (const float*)d_in[2];
  const float* b1  = (const float*)d_in[3];
  const float* W2  = (const float*)d_in[4];
  const float* b2  = (const float*)d_in[5];
  float* out = (float*)d_out;

  char* ws = (char*)d_ws;
  float* scores  = (float*)ws;                          //  147456 B
  int*   idx     = (int*)(ws + 147456);                 //   16384 B
  int*   cidx    = (int*)(ws + 163840);                 //  147456 B
  float* cw      = (float*)(ws + 311296);               //  147456 B
  int*   ccount  = (int*)(ws + 458752);                 //    1024 B
  float* epart   = (float*)(ws + 459776);               // 4718592 B
  float* partial = (float*)(ws + 5178368);              // NP x 2129920 B
  const size_t PSLICE = (size_t)NROW * HH * 4;          // 2129920 B

  hipLaunchKernelGGL(k_scores, dim3((BB * SS) / 4), dim3(256), 0, stream, cls, fm, scores);
  hipLaunchKernelGGL(k_rank,   dim3(BB),            dim3(576), 0, stream,
                     scores, idx, cidx, cw, ccount);
  hipLaunchKernelGGL(k_extra2, dim3(BB, SCH),       dim3(192), 0, stream,
                     cidx, cw, ccount, fm, epart);

  if (ws_size >= 5178368 + 13 * PSLICE) {               // 12 partials + H
    float* H = (float*)(ws + 5178368 + 12 * PSLICE);
    hipLaunchKernelGGL(k_ae1<1>,  dim3(65, 12),      dim3(256), 0, stream,
                       fm, cls, epart, idx, W1, partial);
    hipLaunchKernelGGL(k_hred<12>, dim3(NROW * HH / 1024), dim3(256), 0, stream,
                       partial, b1, H);
    hipLaunchKernelGGL(k_ae2,     dim3(65, 12),      dim3(256), 0, stream, H, W2, b2, out);
  } else {                                              // small-ws fallback
    float* H = (float*)(ws + 5178368 + PSLICE);
    hipLaunchKernelGGL(k_ae1<12>, dim3(65, 1),       dim3(256), 0, stream,
                       fm, cls, epart, idx, W1, partial);
    hipLaunchKernelGGL(k_hred<1>, dim3(NROW * HH / 1024), dim3(256), 0, stream,
                       partial, b1, H);
    hipLaunchKernelGGL(k_ae2,     dim3(65, 12),      dim3(256), 0, stream, H, W2, b2, out);
  }
}